// Round 8
// baseline (486.829 us; speedup 1.0000x reference)
//
#include <hip/hip_runtime.h>

#define BATCH 8
#define NN 32768
#define KK 128
#define NCHUNK 32
#define CHUNK 1024            // NN / NCHUNK
#define NST 16                // super-tiles of 64 n per chunk
#define NITER 8               // CG iterations (kappa ~1.4)

// ---- R8 dual-resolution instrumentation: solvable REP system ----
#define REP_PREP  32
#define REP_GRAM  16
#define REP_RED   8
#define REP_SOLVE 4

typedef __attribute__((ext_vector_type(8)))  _Float16 half8;
typedef __attribute__((ext_vector_type(4)))  _Float16 half4;
typedef __attribute__((ext_vector_type(16))) float    f32x16;

// ---- workspace byte offsets (same as validated R4, ~15.2 MB) ----
#define MT_OFF   0ull                      // multT fp16 [128][32768]
#define WH_OFF   (MT_OFF + 8388608ull)     // wh fp16 [8][32768]
#define DH_OFF   (WH_OFF + 524288ull)      // dh fp16 [8][32768]
#define GP_OFF   (DH_OFF + 524288ull)      // Gp fp16 [8][32][10][1024]
#define MP_OFF   (GP_OFF + 5242880ull)     // Mp f32  [8][32][128]
#define G_OFF    (MP_OFF + 131072ull)      // G  f32  [8][128][128]

// ---------------------------------------------------------------------------
// K0: fused conv + transpose (identical work to R4), REP_PREP-wrapped.
// ---------------------------------------------------------------------------
__global__ __launch_bounds__(256) void prep_kernel(
    const float* __restrict__ data0, const float* __restrict__ mask0,
    const float* __restrict__ mult0, unsigned char* __restrict__ ws)
{
    __shared__ _Float16 t[128][136];
    const int tid = threadIdx.x;
    const int n0  = blockIdx.x * 128;

#pragma unroll 1
    for (int rep = 0; rep < REP_PREP; ++rep) {
        const float* data = data0;  asm volatile("" : "+v"(data));
        const float* mask = mask0;  asm volatile("" : "+v"(mask));
        const float* mult = mult0;  asm volatile("" : "+v"(mult));
        __syncthreads();

        {
            const int b = tid >> 5, q = tid & 31;
            const size_t src = (size_t)b * NN + n0 + q * 4;
            const float4 d4 = *(const float4*)(data + src);
            const float4 m4 = *(const float4*)(mask + src);
            half4 w = { (_Float16)m4.x, (_Float16)m4.y, (_Float16)m4.z, (_Float16)m4.w };
            half4 d = { (_Float16)d4.x, (_Float16)d4.y, (_Float16)d4.z, (_Float16)d4.w };
            *(half4*)((_Float16*)(ws + WH_OFF) + src) = w;
            *(half4*)((_Float16*)(ws + DH_OFF) + src) = d;
        }

        const float4* m4p = (const float4*)mult;
#pragma unroll
        for (int u = 0; u < 16; ++u) {
            const int c16 = u * 256 + tid;
            const int n  = c16 >> 5;
            const int kq = c16 & 31;
            float4 v = m4p[(size_t)(n0 + n) * 32 + kq];
            half4 h = { (_Float16)v.x, (_Float16)v.y, (_Float16)v.z, (_Float16)v.w };
            const int c4s = kq ^ ((n >> 3) & 7);
            *(half4*)&t[n][c4s * 4] = h;
        }
        __syncthreads();

        _Float16* mt = (_Float16*)(ws + MT_OFF);
        const int g = tid & 15;
#pragma unroll
        for (int i = 0; i < 8; ++i) {
            const int k = (tid >> 4) + i * 16;
            half8 v;
#pragma unroll
            for (int j = 0; j < 8; ++j) {
                const int n = g * 8 + j;
                const int cs = (k >> 2) ^ ((n >> 3) & 7);
                v[j] = t[n][cs * 4 + (k & 3)];
            }
            *(half8*)(mt + (size_t)k * NN + n0 + g * 8) = v;
        }
    }
}

// ---------------------------------------------------------------------------
// K1: MFMA gram partials (identical to validated R4), REP_GRAM-wrapped.
// ---------------------------------------------------------------------------
__global__ __launch_bounds__(256, 1) void gram_kernel(
    unsigned char* __restrict__ ws0)
{
    __shared__ unsigned char smem[36864];
    const int tid = threadIdx.x;
    const int b     = blockIdx.x >> 5;
    const int chunk = blockIdx.x & 31;
    const int n0    = chunk * CHUNK;
    const int w = tid >> 6, l = tid & 63;

#pragma unroll 1
    for (int rep = 0; rep < REP_GRAM; ++rep) {
        unsigned char* ws = ws0;  asm volatile("" : "+v"(ws));
        const _Float16* mt = (const _Float16*)(ws + MT_OFF);
        __syncthreads();

        if (tid < 128) {
            half8 wv = *(const half8*)((const _Float16*)(ws + WH_OFF) + (size_t)b * NN + n0 + tid * 8);
            half8 dv = *(const half8*)((const _Float16*)(ws + DH_OFF) + (size_t)b * NN + n0 + tid * 8);
            *(half8*)(smem + 32768 + tid * 16) = wv;
            *(half8*)(smem + 34816 + tid * 16) = dv;
        }

        const int krow = tid >> 3;
        const int gd   = tid & 7;
        const _Float16* gsrc0 = mt + (size_t)krow * NN + n0 + gd * 8;
        const int wslot = (gd ^ (krow & 7)) * 16;

        uint4 S0, S1, S2, S3;
#define GLOAD(st_) { const _Float16* p = gsrc0 + (size_t)(st_) * 64;          \
        S0 = *(const uint4*)(p);                                              \
        S1 = *(const uint4*)(p + (size_t)32 * NN);                            \
        S2 = *(const uint4*)(p + (size_t)64 * NN);                            \
        S3 = *(const uint4*)(p + (size_t)96 * NN); }
#define DSWRITE(buf_) { unsigned char* bp = smem + (buf_) * 16384 + krow * 128 + wslot; \
        *(uint4*)(bp)         = S0;  *(uint4*)(bp + 4096)  = S1;              \
        *(uint4*)(bp + 8192)  = S2;  *(uint4*)(bp + 12288) = S3; }

        const int frow  = (l & 31) * 128;
        const int fslot = ((w * 2 + (l >> 5)) ^ (l & 7)) * 16;
        const int wdoff = w * 32 + (l >> 5) * 16;

        f32x16 a00 = {}, a01 = {}, a02 = {}, a03 = {}, a11 = {},
               a12 = {}, a13 = {}, a22 = {}, a23 = {}, a33 = {};
        float macc0 = 0.f, macc1 = 0.f, macc2 = 0.f, macc3 = 0.f;

        GLOAD(0);
        __syncthreads();
        DSWRITE(0);
        GLOAD(1);
        __syncthreads();

#pragma unroll 2
        for (int st = 0; st < NST; ++st) {
            const int cur = st & 1;
            if (st < NST - 1) {
                DSWRITE(cur ^ 1);
                if (st < NST - 2) GLOAD(st + 2);
            }
            const unsigned char* tb = smem + cur * 16384;
            const half8 wf = *(const half8*)(smem + 32768 + st * 128 + wdoff);
            const half8 df = *(const half8*)(smem + 34816 + st * 128 + wdoff);
            half8 f0 = *(const half8*)(tb +     0 + frow + fslot) * wf;
            half8 f1 = *(const half8*)(tb +  4096 + frow + fslot) * wf;
            half8 f2 = *(const half8*)(tb +  8192 + frow + fslot) * wf;
            half8 f3 = *(const half8*)(tb + 12288 + frow + fslot) * wf;
#pragma unroll
            for (int j = 0; j < 8; ++j) {
                const float dj = (float)df[j];
                macc0 = fmaf((float)f0[j], dj, macc0);
                macc1 = fmaf((float)f1[j], dj, macc1);
                macc2 = fmaf((float)f2[j], dj, macc2);
                macc3 = fmaf((float)f3[j], dj, macc3);
            }
            a00 = __builtin_amdgcn_mfma_f32_32x32x16_f16(f0, f0, a00, 0, 0, 0);
            a01 = __builtin_amdgcn_mfma_f32_32x32x16_f16(f0, f1, a01, 0, 0, 0);
            a02 = __builtin_amdgcn_mfma_f32_32x32x16_f16(f0, f2, a02, 0, 0, 0);
            a03 = __builtin_amdgcn_mfma_f32_32x32x16_f16(f0, f3, a03, 0, 0, 0);
            a11 = __builtin_amdgcn_mfma_f32_32x32x16_f16(f1, f1, a11, 0, 0, 0);
            a12 = __builtin_amdgcn_mfma_f32_32x32x16_f16(f1, f2, a12, 0, 0, 0);
            a13 = __builtin_amdgcn_mfma_f32_32x32x16_f16(f1, f3, a13, 0, 0, 0);
            a22 = __builtin_amdgcn_mfma_f32_32x32x16_f16(f2, f2, a22, 0, 0, 0);
            a23 = __builtin_amdgcn_mfma_f32_32x32x16_f16(f2, f3, a23, 0, 0, 0);
            a33 = __builtin_amdgcn_mfma_f32_32x32x16_f16(f3, f3, a33, 0, 0, 0);
            __syncthreads();
        }

        {
            float* M = (float*)(smem + 32768);
            const int base = (w * 2 + (l >> 5)) * 128 + (l & 31);
            M[base +  0] = macc0;  M[base + 32] = macc1;
            M[base + 64] = macc2;  M[base + 96] = macc3;
        }
        _Float16* Gp = (_Float16*)(ws + GP_OFF) + (size_t)(b * NCHUNK + chunk) * 10240;
        float* Mp = (float*)(ws + MP_OFF) + (size_t)(b * NCHUNK + chunk) * KK;
        float* R = (float*)smem;

#define PHASE(p_, A0_, A1_)                                                    \
    {                                                                          \
        *(f32x16*)(R + (w * 2 + 0) * 1024 + l * 16) = A0_;                     \
        *(f32x16*)(R + (w * 2 + 1) * 1024 + l * 16) = A1_;                     \
        __syncthreads();                                                       \
        _Pragma("unroll")                                                      \
        for (int pass = 0; pass < 2; ++pass) {                                 \
            const int e = pass * 1024 + tid * 4;                               \
            float4 s0 = *(float4*)(R + e);                                     \
            float4 s1 = *(float4*)(R + 2048 + e);                              \
            float4 s2 = *(float4*)(R + 4096 + e);                              \
            float4 s3 = *(float4*)(R + 6144 + e);                              \
            float sx = s0.x + s1.x + s2.x + s3.x;                              \
            float sy = s0.y + s1.y + s2.y + s3.y;                              \
            float sz = s0.z + s1.z + s2.z + s3.z;                              \
            float sw = s0.w + s1.w + s2.w + s3.w;                              \
            half4 h = { (_Float16)sx, (_Float16)sy, (_Float16)sz, (_Float16)sw }; \
            *(half4*)(Gp + (p_) * 2048 + e) = h;                               \
        }                                                                      \
        if ((p_) == 0 && tid < 128) {                                          \
            const float* M = (const float*)(smem + 32768);                     \
            float s = 0.f;                                                     \
            _Pragma("unroll")                                                  \
            for (int c8 = 0; c8 < 8; ++c8) s += M[c8 * 128 + tid];             \
            Mp[tid] = s;                                                       \
        }                                                                      \
        __syncthreads();                                                       \
    }

        PHASE(0, a00, a01)
        PHASE(1, a02, a03)
        PHASE(2, a11, a12)
        PHASE(3, a13, a22)
        PHASE(4, a23, a33)
#undef PHASE
#undef GLOAD
#undef DSWRITE
    }
}

// ---------------------------------------------------------------------------
// K2: WIDE reduce (validated R4 structure), REP_RED-wrapped.
// ---------------------------------------------------------------------------
__global__ __launch_bounds__(256) void reduce_kernel(
    const float* __restrict__ sig, unsigned char* __restrict__ ws0)
{
    const int tid = threadIdx.x;
    const int b  = blockIdx.x / 5;
    const int t2 = blockIdx.x % 5;

    const int e_local = tid * 8;
    const int tile = t2 * 2 + (e_local >> 10);
    const int off  = e_local & 1023;
    const int lane = off >> 4;
    const int r0   = off & 15;

    static const int TT[10] = {0,0,0,0,1,1,1,2,2,3};
    static const int UU[10] = {0,1,2,3,1,2,3,2,3,3};
    const int tt = TT[tile], uu = UU[tile];
    const int C = uu * 32 + (lane & 31);

#pragma unroll 1
    for (int rep = 0; rep < REP_RED; ++rep) {
        unsigned char* ws = ws0;  asm volatile("" : "+v"(ws));
        const _Float16* Gp = (const _Float16*)(ws + GP_OFF)
                           + (size_t)b * NCHUNK * 10240 + (size_t)t2 * 2048 + e_local;
        float s[8] = {0.f,0.f,0.f,0.f,0.f,0.f,0.f,0.f};
#pragma unroll
        for (int ch = 0; ch < NCHUNK; ++ch) {
            half8 v = *(const half8*)(Gp + (size_t)ch * 10240);
#pragma unroll
            for (int j = 0; j < 8; ++j) s[j] += (float)v[j];
        }

        float* G = (float*)(ws + G_OFF) + (size_t)b * 16384;
        const float sg = sig[0];
#pragma unroll
        for (int j = 0; j < 8; ++j) {
            const int reg = r0 + j;
            const int row = (reg & 3) + 8 * (reg >> 2) + 4 * (lane >> 5);
            const int Rr = tt * 32 + row;
            float v = s[j];
            G[Rr * KK + C] = (Rr == C) ? v + sg : v;
            if (tt != uu) G[C * KK + Rr] = v;
        }
    }
}

// ---------------------------------------------------------------------------
// K3: CG solve, UNSPILLED (Gr[64] per thread, h-halved rows), REP_SOLVE-wrapped.
// ---------------------------------------------------------------------------
__device__ __forceinline__ float blockDot4(float a, float bvl, float* red)
{
    float v = a * bvl;
#pragma unroll
    for (int off = 32; off > 0; off >>= 1) v += __shfl_down(v, off, 64);
    const int wid = threadIdx.x >> 6;
    if ((threadIdx.x & 63) == 0) red[wid] = v;
    __syncthreads();
    float s = (red[0] + red[1]) + (red[2] + red[3]);
    __syncthreads();
    return s;
}

__global__ __launch_bounds__(256, 1) void solve_kernel(
    const unsigned char* __restrict__ ws0, float* __restrict__ out)
{
    __shared__ float ps[KK];
    __shared__ float qex[256];
    __shared__ float red[4];

    const int tid = threadIdx.x;
    const int b   = blockIdx.x;
    const int i   = tid & 127;
    const int h   = tid >> 7;

#pragma unroll 1
    for (int rep = 0; rep < REP_SOLVE; ++rep) {
        const unsigned char* ws = ws0;  asm volatile("" : "+v"(ws));
        const float* G  = (const float*)(ws + G_OFF) + (size_t)b * 16384;
        const float* Mp = (const float*)(ws + MP_OFF) + (size_t)b * NCHUNK * KK;
        __syncthreads();

        float Gr[64];
#pragma unroll
        for (int j = 0; j < 64; ++j) Gr[j] = G[(size_t)(h * 64 + j) * KK + i];

        float mvv = 0.f;
#pragma unroll
        for (int ch = 0; ch < NCHUNK; ++ch) mvv += Mp[ch * KK + i];

        float x = 0.f, r = mvv, p = r;
        ps[i] = p;
        float rs = blockDot4(r, r, red);

        for (int it = 0; it < NITER; ++it) {
            float q0 = 0.f, q1 = 0.f, q2 = 0.f, q3 = 0.f;
            const float* psh = ps + h * 64;
#pragma unroll
            for (int u = 0; u < 16; ++u) {
                float4 pv = *(const float4*)(psh + 4 * u);
                q0 = fmaf(Gr[4 * u + 0], pv.x, q0);
                q1 = fmaf(Gr[4 * u + 1], pv.y, q1);
                q2 = fmaf(Gr[4 * u + 2], pv.z, q2);
                q3 = fmaf(Gr[4 * u + 3], pv.w, q3);
            }
            qex[tid] = (q0 + q1) + (q2 + q3);
            __syncthreads();
            const float q = qex[i] + qex[128 + i];

            float pq    = blockDot4(p, q, red);
            float alpha = rs / (pq + 1e-30f);
            x = fmaf(alpha, p, x);
            r = fmaf(-alpha, q, r);
            float rs2  = blockDot4(r, r, red);
            float beta = rs2 / (rs + 1e-30f);
            rs = rs2;
            p  = fmaf(beta, p, r);
            __syncthreads();
            ps[i] = p;
            __syncthreads();
        }
        if (h == 0) out[(size_t)b * KK + i] = x;
    }
}

// ---------------------------------------------------------------------------
extern "C" void kernel_launch(void* const* d_in, const int* in_sizes, int n_in,
                              void* d_out, int out_size, void* d_ws, size_t ws_size,
                              hipStream_t stream)
{
    const float* data = (const float*)d_in[0];
    const float* mask = (const float*)d_in[1];
    const float* mult = (const float*)d_in[2];
    const float* sig  = (const float*)d_in[3];
    unsigned char* ws = (unsigned char*)d_ws;
    float* out = (float*)d_out;

    prep_kernel  <<<256, 256, 0, stream>>>(data, mask, mult, ws);
    gram_kernel  <<<BATCH * NCHUNK, 256, 0, stream>>>(ws);
    reduce_kernel<<<BATCH * 5, 256, 0, stream>>>(sig, ws);
    solve_kernel <<<BATCH, 256, 0, stream>>>(ws, out);
}

// Round 9
// 102.067 us; speedup vs baseline: 4.7697x; 4.7697x over previous
//
#include <hip/hip_runtime.h>

#define BATCH 8
#define NN 32768
#define KK 128
#define NCHUNK 32
#define CHUNK 1024            // NN / NCHUNK
#define NST 16                // super-tiles of 64 n per chunk
#define NITER 8               // CG iterations (kappa ~1.4)

typedef __attribute__((ext_vector_type(8)))  _Float16 half8;
typedef __attribute__((ext_vector_type(4)))  _Float16 half4;
typedef __attribute__((ext_vector_type(16))) float    f32x16;

// ---- workspace byte offsets (~15.2 MB) ----
#define MT_OFF   0ull                      // multT fp16 [128][32768]
#define WH_OFF   (MT_OFF + 8388608ull)     // wh fp16 [8][32768]
#define DH_OFF   (WH_OFF + 524288ull)      // dh fp16 [8][32768]
#define GP_OFF   (DH_OFF + 524288ull)      // Gp fp16 [8][32][10][1024]
#define MP_OFF   (GP_OFF + 5242880ull)     // Mp f32  [8][32][128]
#define G_OFF    (MP_OFF + 131072ull)      // G  f32  [8][128][128]

// ---------------------------------------------------------------------------
// K0: fused conv + transpose (validated R4).
// ---------------------------------------------------------------------------
__global__ __launch_bounds__(256) void prep_kernel(
    const float* __restrict__ data, const float* __restrict__ mask,
    const float* __restrict__ mult, unsigned char* __restrict__ ws)
{
    __shared__ _Float16 t[128][136];
    const int tid = threadIdx.x;
    const int n0  = blockIdx.x * 128;

    {
        const int b = tid >> 5, q = tid & 31;
        const size_t src = (size_t)b * NN + n0 + q * 4;
        const float4 d4 = *(const float4*)(data + src);
        const float4 m4 = *(const float4*)(mask + src);
        half4 w = { (_Float16)m4.x, (_Float16)m4.y, (_Float16)m4.z, (_Float16)m4.w };
        half4 d = { (_Float16)d4.x, (_Float16)d4.y, (_Float16)d4.z, (_Float16)d4.w };
        *(half4*)((_Float16*)(ws + WH_OFF) + src) = w;
        *(half4*)((_Float16*)(ws + DH_OFF) + src) = d;
    }

    const float4* m4p = (const float4*)mult;
#pragma unroll
    for (int u = 0; u < 16; ++u) {
        const int c16 = u * 256 + tid;
        const int n  = c16 >> 5;
        const int kq = c16 & 31;
        float4 v = m4p[(size_t)(n0 + n) * 32 + kq];
        half4 h = { (_Float16)v.x, (_Float16)v.y, (_Float16)v.z, (_Float16)v.w };
        const int c4s = kq ^ ((n >> 3) & 7);
        *(half4*)&t[n][c4s * 4] = h;
    }
    __syncthreads();

    _Float16* mt = (_Float16*)(ws + MT_OFF);
    const int g = tid & 15;
#pragma unroll
    for (int i = 0; i < 8; ++i) {
        const int k = (tid >> 4) + i * 16;
        half8 v;
#pragma unroll
        for (int j = 0; j < 8; ++j) {
            const int n = g * 8 + j;
            const int cs = (k >> 2) ^ ((n >> 3) & 7);
            v[j] = t[n][cs * 4 + (k & 3)];
        }
        *(half8*)(mt + (size_t)k * NN + n0 + g * 8) = v;
    }
}

// ---------------------------------------------------------------------------
// K1: MFMA gram partials, 512 threads / 8 waves (2 waves/SIMD).
// Wave (wq = tid>>8, wn = (tid>>6)&3): wn = n-octet-pair role (as R4),
// wq splits the 10 upper-tri tiles 5/5 and the m-dot 2/2.
// Epilogue regions stored [c2][lane] -> conflict-free ds_write_b128
// (R8 PMC: 1.24M conflict-cycles/rep came from the old [lane][c2] writes).
// Gp element order is now off = c2*256 + lane*4 + rj  (reg = c2*4+rj).
// ---------------------------------------------------------------------------
__global__ __launch_bounds__(512, 1) void gram_kernel(
    unsigned char* __restrict__ ws)
{
    __shared__ unsigned char smem[36864];     // 2x16KB tiles | 4KB wd/M
    const int tid = threadIdx.x;
    const int b     = blockIdx.x >> 5;
    const int chunk = blockIdx.x & 31;
    const int n0    = chunk * CHUNK;
    const int wn = (tid >> 6) & 3;
    const int wq = tid >> 8;
    const int l  = tid & 63;
    const int hi = l >> 5;

    const _Float16* mt = (const _Float16*)(ws + MT_OFF);

    if (tid < 128) {
        half8 wv = *(const half8*)((const _Float16*)(ws + WH_OFF) + (size_t)b * NN + n0 + tid * 8);
        half8 dv = *(const half8*)((const _Float16*)(ws + DH_OFF) + (size_t)b * NN + n0 + tid * 8);
        *(half8*)(smem + 32768 + tid * 16) = wv;
        *(half8*)(smem + 34816 + tid * 16) = dv;
    }

    // staging: 512 threads cover rows 0..63 (S0) and 64..127 (S1)
    const int krow = tid >> 3;                  // 0..63
    const int gd   = tid & 7;
    const _Float16* gsrc0 = mt + (size_t)krow * NN + n0 + gd * 8;
    const int wslot = (gd ^ (krow & 7)) * 16;

    uint4 S0, S1;
#define GLOAD(st_) { const _Float16* p = gsrc0 + (size_t)(st_) * 64;          \
        S0 = *(const uint4*)(p);                                              \
        S1 = *(const uint4*)(p + (size_t)64 * NN); }
#define DSWRITE(buf_) { unsigned char* bp = smem + (buf_) * 16384 + krow * 128 + wslot; \
        *(uint4*)(bp)        = S0;  *(uint4*)(bp + 8192) = S1; }

    const int frow  = (l & 31) * 128;
    const int fslot = ((wn * 2 + hi) ^ (l & 7)) * 16;
    const int wdoff = wn * 32 + hi * 16;

    f32x16 A0 = {}, A1 = {}, A2 = {}, A3 = {}, A4 = {};
    float macX = 0.f, macY = 0.f;

    GLOAD(0);
    __syncthreads();
    DSWRITE(0);
    GLOAD(1);
    __syncthreads();

#pragma unroll 2
    for (int st = 0; st < NST; ++st) {
        const int cur = st & 1;
        if (st < NST - 1) {
            DSWRITE(cur ^ 1);
            if (st < NST - 2) GLOAD(st + 2);
        }
        const unsigned char* tb = smem + cur * 16384;
        const half8 wf = *(const half8*)(smem + 32768 + st * 128 + wdoff);
        const half8 df = *(const half8*)(smem + 34816 + st * 128 + wdoff);
        half8 f1 = *(const half8*)(tb +  4096 + frow + fslot) * wf;
        half8 f2 = *(const half8*)(tb +  8192 + frow + fslot) * wf;
        half8 f3 = *(const half8*)(tb + 12288 + frow + fslot) * wf;
        if (wq == 0) {
            half8 f0 = *(const half8*)(tb + frow + fslot) * wf;
#pragma unroll
            for (int j = 0; j < 8; ++j) {
                const float dj = (float)df[j];
                macX = fmaf((float)f0[j], dj, macX);
                macY = fmaf((float)f1[j], dj, macY);
            }
            A0 = __builtin_amdgcn_mfma_f32_32x32x16_f16(f0, f0, A0, 0, 0, 0);
            A1 = __builtin_amdgcn_mfma_f32_32x32x16_f16(f0, f1, A1, 0, 0, 0);
            A2 = __builtin_amdgcn_mfma_f32_32x32x16_f16(f0, f2, A2, 0, 0, 0);
            A3 = __builtin_amdgcn_mfma_f32_32x32x16_f16(f0, f3, A3, 0, 0, 0);
            A4 = __builtin_amdgcn_mfma_f32_32x32x16_f16(f1, f1, A4, 0, 0, 0);
        } else {
#pragma unroll
            for (int j = 0; j < 8; ++j) {
                const float dj = (float)df[j];
                macX = fmaf((float)f2[j], dj, macX);
                macY = fmaf((float)f3[j], dj, macY);
            }
            A0 = __builtin_amdgcn_mfma_f32_32x32x16_f16(f1, f2, A0, 0, 0, 0);
            A1 = __builtin_amdgcn_mfma_f32_32x32x16_f16(f1, f3, A1, 0, 0, 0);
            A2 = __builtin_amdgcn_mfma_f32_32x32x16_f16(f2, f2, A2, 0, 0, 0);
            A3 = __builtin_amdgcn_mfma_f32_32x32x16_f16(f2, f3, A3, 0, 0, 0);
            A4 = __builtin_amdgcn_mfma_f32_32x32x16_f16(f3, f3, A4, 0, 0, 0);
        }
        __syncthreads();
    }

    // ---- epilogue ----
    float* Rb = (float*)smem;                 // 8 regions x 4KB
    float* M  = (float*)(smem + 32768);       // 8 x 128 f32 m-partials
    _Float16* Gp = (_Float16*)(ws + GP_OFF) + (size_t)(b * NCHUNK + chunk) * 10240;
    float* Mp = (float*)(ws + MP_OFF) + (size_t)(b * NCHUNK + chunk) * KK;

    // m partials: wq0 -> k 0..63, wq1 -> k 64..127; rows wn*2+hi
    {
        const int row = (wn * 2 + hi) * 128 + wq * 64 + (l & 31);
        M[row]      = macX;
        M[row + 32] = macY;
    }

    // conflict-free region write: [c2][lane] layout
#define WR(A_, r_) {                                                           \
        *(float4*)(Rb + (r_) * 1024 +   0 + l * 4) = make_float4(A_[0],  A_[1],  A_[2],  A_[3]);  \
        *(float4*)(Rb + (r_) * 1024 + 256 + l * 4) = make_float4(A_[4],  A_[5],  A_[6],  A_[7]);  \
        *(float4*)(Rb + (r_) * 1024 + 512 + l * 4) = make_float4(A_[8],  A_[9],  A_[10], A_[11]); \
        *(float4*)(Rb + (r_) * 1024 + 768 + l * 4) = make_float4(A_[12], A_[13], A_[14], A_[15]); }

#define RED(P_)                                                                \
    {                                                                          \
        __syncthreads();                                                       \
        const int e = tid * 4;                                                 \
        const int gsel = e >> 10, off = e & 1023;                              \
        float4 s0 = *(float4*)(Rb + (gsel * 4 + 0) * 1024 + off);              \
        float4 s1 = *(float4*)(Rb + (gsel * 4 + 1) * 1024 + off);              \
        float4 s2 = *(float4*)(Rb + (gsel * 4 + 2) * 1024 + off);              \
        float4 s3 = *(float4*)(Rb + (gsel * 4 + 3) * 1024 + off);              \
        half4 hv = { (_Float16)(s0.x + s1.x + s2.x + s3.x),                    \
                     (_Float16)(s0.y + s1.y + s2.y + s3.y),                    \
                     (_Float16)(s0.z + s1.z + s2.z + s3.z),                    \
                     (_Float16)(s0.w + s1.w + s2.w + s3.w) };                  \
        *(half4*)(Gp + (2 * (P_) + gsel) * 1024 + off) = hv;                   \
        if ((P_) == 0 && tid < 128) {                                          \
            float s = 0.f;                                                     \
            _Pragma("unroll")                                                  \
            for (int r8 = 0; r8 < 8; ++r8) s += M[r8 * 128 + tid];             \
            Mp[tid] = s;                                                       \
        }                                                                      \
        __syncthreads();                                                       \
    }

    // P0: tiles 0,1 (wq0 L0,L1)
    if (wq == 0) { WR(A0, wn) WR(A1, 4 + wn) }
    RED(0)
    // P1: tiles 2,3 (wq0 L2,L3)
    if (wq == 0) { WR(A2, wn) WR(A3, 4 + wn) }
    RED(1)
    // P2: tiles 4 (wq0 L4), 5 (wq1 L0)
    if (wq == 0) { WR(A4, wn) } else { WR(A0, 4 + wn) }
    RED(2)
    // P3: tiles 6,7 (wq1 L1,L2)
    if (wq == 1) { WR(A1, wn) WR(A2, 4 + wn) }
    RED(3)
    // P4: tiles 8,9 (wq1 L3,L4)
    if (wq == 1) { WR(A3, wn) WR(A4, 4 + wn) }
    RED(4)
#undef WR
#undef RED
#undef GLOAD
#undef DSWRITE
}

// ---------------------------------------------------------------------------
// K2: wide reduce -> G f32 + sigma^2 I.  NEW Gp order decode:
// off = c2*256 + lane*4 + rj; reg = c2*4+rj; row=(reg&3)+8*(reg>>2)+4*(lane>>5).
// ---------------------------------------------------------------------------
__global__ __launch_bounds__(256) void reduce_kernel(
    const float* __restrict__ sig, unsigned char* __restrict__ ws)
{
    const int tid = threadIdx.x;
    const int b  = blockIdx.x / 5;
    const int t2 = blockIdx.x % 5;

    const int e_local = tid * 8;
    const int tile = t2 * 2 + (e_local >> 10);
    const int off0 = e_local & 1023;
    const int c2 = off0 >> 8;
    const int l0 = (off0 >> 2) & 63;

    static const int TT[10] = {0,0,0,0,1,1,1,2,2,3};
    static const int UU[10] = {0,1,2,3,1,2,3,2,3,3};
    const int tt = TT[tile], uu = UU[tile];

    const _Float16* Gp = (const _Float16*)(ws + GP_OFF)
                       + (size_t)b * NCHUNK * 10240 + (size_t)t2 * 2048 + e_local;
    float s[8] = {0.f,0.f,0.f,0.f,0.f,0.f,0.f,0.f};
#pragma unroll
    for (int ch = 0; ch < NCHUNK; ++ch) {
        half8 v = *(const half8*)(Gp + (size_t)ch * 10240);
#pragma unroll
        for (int j = 0; j < 8; ++j) s[j] += (float)v[j];
    }

    float* G = (float*)(ws + G_OFF) + (size_t)b * 16384;
    const float sg = sig[0];
#pragma unroll
    for (int j = 0; j < 8; ++j) {
        const int ll = l0 + (j >> 2);
        const int rj = j & 3;
        const int row = rj + 8 * c2 + 4 * (ll >> 5);
        const int col = ll & 31;
        const int Rr = tt * 32 + row;
        const int C  = uu * 32 + col;
        float v = s[j];
        G[Rr * KK + C] = (Rr == C) ? v + sg : v;
        if (tt != uu) G[C * KK + Rr] = v;
    }
}

// ---------------------------------------------------------------------------
// K3: CG solve, unspilled: thread (i = tid&127, h = tid>>7) holds Gr[64].
// ---------------------------------------------------------------------------
__device__ __forceinline__ float blockDot4(float a, float bvl, float* red)
{
    float v = a * bvl;
#pragma unroll
    for (int off = 32; off > 0; off >>= 1) v += __shfl_down(v, off, 64);
    const int wid = threadIdx.x >> 6;
    if ((threadIdx.x & 63) == 0) red[wid] = v;
    __syncthreads();
    float s = (red[0] + red[1]) + (red[2] + red[3]);
    __syncthreads();
    return s;
}

__global__ __launch_bounds__(256, 1) void solve_kernel(
    const unsigned char* __restrict__ ws, float* __restrict__ out)
{
    __shared__ float ps[KK];
    __shared__ float qex[256];
    __shared__ float red[4];

    const int tid = threadIdx.x;
    const int b   = blockIdx.x;
    const int i   = tid & 127;
    const int h   = tid >> 7;

    const float* G  = (const float*)(ws + G_OFF) + (size_t)b * 16384;
    const float* Mp = (const float*)(ws + MP_OFF) + (size_t)b * NCHUNK * KK;

    float Gr[64];
#pragma unroll
    for (int j = 0; j < 64; ++j) Gr[j] = G[(size_t)(h * 64 + j) * KK + i];

    float mvv = 0.f;
#pragma unroll
    for (int ch = 0; ch < NCHUNK; ++ch) mvv += Mp[ch * KK + i];

    float x = 0.f, r = mvv, p = r;
    ps[i] = p;
    float rs = blockDot4(r, r, red);

    for (int it = 0; it < NITER; ++it) {
        float q0 = 0.f, q1 = 0.f, q2 = 0.f, q3 = 0.f;
        const float* psh = ps + h * 64;
#pragma unroll
        for (int u = 0; u < 16; ++u) {
            float4 pv = *(const float4*)(psh + 4 * u);
            q0 = fmaf(Gr[4 * u + 0], pv.x, q0);
            q1 = fmaf(Gr[4 * u + 1], pv.y, q1);
            q2 = fmaf(Gr[4 * u + 2], pv.z, q2);
            q3 = fmaf(Gr[4 * u + 3], pv.w, q3);
        }
        qex[tid] = (q0 + q1) + (q2 + q3);
        __syncthreads();
        const float q = qex[i] + qex[128 + i];

        float pq    = blockDot4(p, q, red);
        float alpha = rs / (pq + 1e-30f);
        x = fmaf(alpha, p, x);
        r = fmaf(-alpha, q, r);
        float rs2  = blockDot4(r, r, red);
        float beta = rs2 / (rs + 1e-30f);
        rs = rs2;
        p  = fmaf(beta, p, r);
        __syncthreads();
        ps[i] = p;
        __syncthreads();
    }
    if (h == 0) out[(size_t)b * KK + i] = x;
}

// ---------------------------------------------------------------------------
extern "C" void kernel_launch(void* const* d_in, const int* in_sizes, int n_in,
                              void* d_out, int out_size, void* d_ws, size_t ws_size,
                              hipStream_t stream)
{
    const float* data = (const float*)d_in[0];
    const float* mask = (const float*)d_in[1];
    const float* mult = (const float*)d_in[2];
    const float* sig  = (const float*)d_in[3];
    unsigned char* ws = (unsigned char*)d_ws;
    float* out = (float*)d_out;

    prep_kernel  <<<256, 256, 0, stream>>>(data, mask, mult, ws);
    gram_kernel  <<<256, 512, 0, stream>>>(ws);
    reduce_kernel<<<BATCH * 5, 256, 0, stream>>>(sig, ws);
    solve_kernel <<<BATCH, 256, 0, stream>>>(ws, out);
}